// Round 1
// baseline (575.285 us; speedup 1.0000x reference)
//
#include <hip/hip_runtime.h>

#define NN 100000
#define NE 1600000
#define DD 64

static constexpr int SCAN_BLOCK = 1024;
static constexpr int NB = (NN + SCAN_BLOCK - 1) / SCAN_BLOCK; // 98

// ---- CSR build ----

__global__ void k_hist(const int* __restrict__ dst, int* __restrict__ cnt) {
  int stride = gridDim.x * blockDim.x;
  for (int i = blockIdx.x * blockDim.x + threadIdx.x; i < NE; i += stride)
    atomicAdd(&cnt[dst[i]], 1);
}

__global__ void k_dis(const int* __restrict__ cnt, float* __restrict__ dis) {
  int i = blockIdx.x * blockDim.x + threadIdx.x;
  if (i < NN) dis[i] = rsqrtf((float)(cnt[i] + 1)); // deg includes self-loop, >=1
}

__global__ void k_scan1(const int* __restrict__ cnt, int* __restrict__ rowptr,
                        int* __restrict__ bsum) {
  __shared__ int sh[256];
  int t = threadIdx.x, b = blockIdx.x;
  int base = b * SCAN_BLOCK + t * 4;
  int v0 = (base + 0 < NN) ? cnt[base + 0] : 0;
  int v1 = (base + 1 < NN) ? cnt[base + 1] : 0;
  int v2 = (base + 2 < NN) ? cnt[base + 2] : 0;
  int v3 = (base + 3 < NN) ? cnt[base + 3] : 0;
  int s = v0 + v1 + v2 + v3;
  sh[t] = s;
  __syncthreads();
  for (int off = 1; off < 256; off <<= 1) {
    int x = (t >= off) ? sh[t - off] : 0;
    __syncthreads();
    sh[t] += x;
    __syncthreads();
  }
  int ex = sh[t] - s; // exclusive prefix of this thread's 4-chunk
  if (t == 255) bsum[b] = sh[255];
  if (base + 0 < NN) rowptr[base + 0] = ex; ex += v0;
  if (base + 1 < NN) rowptr[base + 1] = ex; ex += v1;
  if (base + 2 < NN) rowptr[base + 2] = ex; ex += v2;
  if (base + 3 < NN) rowptr[base + 3] = ex;
}

__global__ void k_scan2(int* __restrict__ bsum, int* __restrict__ rowptr) {
  if (threadIdx.x == 0 && blockIdx.x == 0) {
    int run = 0;
    for (int b = 0; b < NB; ++b) { int t = bsum[b]; bsum[b] = run; run += t; }
    rowptr[NN] = run; // == NE
  }
}

__global__ void k_scan3(int* __restrict__ rowptr, const int* __restrict__ bsum,
                        int* __restrict__ rowfill) {
  int i = blockIdx.x * blockDim.x + threadIdx.x;
  if (i < NN) {
    int v = rowptr[i] + bsum[i / SCAN_BLOCK];
    rowptr[i] = v;
    rowfill[i] = v;
  }
}

__global__ void k_fill(const int* __restrict__ src, const int* __restrict__ dst,
                       const float* __restrict__ dis, int* __restrict__ rowfill,
                       int* __restrict__ col, float* __restrict__ wgt) {
  int stride = gridDim.x * blockDim.x;
  for (int i = blockIdx.x * blockDim.x + threadIdx.x; i < NE; i += stride) {
    int s = src[i], d = dst[i];
    int pos = atomicAdd(&rowfill[d], 1);
    col[pos] = s;
    wgt[pos] = dis[s] * dis[d];
  }
}

// ---- fused layer: out = [relu]( (S*h) @ W + b ) ----
// One wave per node (grid-strided). lane = feature index.
// acc (lane k holds aggregated feature k) -> epilogue GEMM via shfl broadcast.

__global__ __launch_bounds__(256) void k_layer(
    const float* __restrict__ h, const int* __restrict__ rowptr,
    const int* __restrict__ col, const float* __restrict__ wgt,
    const float* __restrict__ dis, const float* __restrict__ W,
    const float* __restrict__ bias, float* __restrict__ out, int relu)
{
  const int lane = threadIdx.x & 63;
  const int wid  = (blockIdx.x * blockDim.x + threadIdx.x) >> 6;
  const int nw   = (gridDim.x * blockDim.x) >> 6;

  // per-lane W column (lane j holds W[:, j]); amortized over ~NN/nw nodes
  float w[64];
  #pragma unroll
  for (int k = 0; k < 64; ++k) w[k] = W[k * 64 + lane];
  const float bv = bias[lane];

  for (int node = wid; node < NN; node += nw) {
    const int r0 = rowptr[node], r1 = rowptr[node + 1];
    const float di = dis[node];
    // self-loop contribution: norm = dis[i]^2 = 1/deg[i]
    float acc = di * di * h[(size_t)node * 64 + lane];

    int e = r0;
    for (; e + 4 <= r1; e += 4) {
      int   c0 = col[e + 0], c1 = col[e + 1], c2 = col[e + 2], c3 = col[e + 3];
      float w0 = wgt[e + 0], w1 = wgt[e + 1], w2 = wgt[e + 2], w3 = wgt[e + 3];
      float g0 = h[(size_t)c0 * 64 + lane];
      float g1 = h[(size_t)c1 * 64 + lane];
      float g2 = h[(size_t)c2 * 64 + lane];
      float g3 = h[(size_t)c3 * 64 + lane];
      acc = fmaf(w0, g0, acc);
      acc = fmaf(w1, g1, acc);
      acc = fmaf(w2, g2, acc);
      acc = fmaf(w3, g3, acc);
    }
    for (; e < r1; ++e)
      acc = fmaf(wgt[e], h[(size_t)col[e] * 64 + lane], acc);

    // epilogue GEMM: o_j = b_j + sum_k acc_k * W[k][j]
    float o = bv;
    #pragma unroll
    for (int k = 0; k < 64; ++k)
      o = fmaf(__shfl(acc, k), w[k], o);
    if (relu) o = fmaxf(o, 0.0f);
    out[(size_t)node * 64 + lane] = o;
  }
}

extern "C" void kernel_launch(void* const* d_in, const int* in_sizes, int n_in,
                              void* d_out, int out_size, void* d_ws, size_t ws_size,
                              hipStream_t stream) {
  const float* x  = (const float*)d_in[0];
  const int*   ei = (const int*)d_in[1];
  const float* W1 = (const float*)d_in[2];
  const float* b1 = (const float*)d_in[3];
  const float* W2 = (const float*)d_in[4];
  const float* b2 = (const float*)d_in[5];
  const float* W3 = (const float*)d_in[6];
  const float* b3 = (const float*)d_in[7];
  float* out = (float*)d_out;

  const int* src = ei;        // edge_index[0], length NE
  const int* dst = ei + NE;   // edge_index[1], length NE

  char* ws = (char*)d_ws;
  size_t off = 0;
  auto alloc = [&](size_t bytes) {
    void* p = ws + off;
    off = (off + bytes + 255) & ~(size_t)255;
    return p;
  };
  int*   cnt    = (int*)alloc((size_t)NN * 4);        // later reused as rowfill
  int*   rowptr = (int*)alloc((size_t)(NN + 1) * 4);
  float* dis    = (float*)alloc((size_t)NN * 4);
  int*   bsum   = (int*)alloc((size_t)NB * 4);
  int*   col    = (int*)alloc((size_t)NE * 4);
  float* wgt    = (float*)alloc((size_t)NE * 4);
  float* bufA   = (float*)alloc((size_t)NN * DD * 4);
  (void)ws_size; (void)in_sizes; (void)n_in; (void)out_size;

  hipMemsetAsync(cnt, 0, (size_t)NN * 4, stream);
  k_hist <<<2048, 256, 0, stream>>>(dst, cnt);
  k_dis  <<<(NN + 255) / 256, 256, 0, stream>>>(cnt, dis);
  k_scan1<<<NB, 256, 0, stream>>>(cnt, rowptr, bsum);
  k_scan2<<<1, 64, 0, stream>>>(bsum, rowptr);
  k_scan3<<<(NN + 255) / 256, 256, 0, stream>>>(rowptr, bsum, cnt /*rowfill*/);
  k_fill <<<2048, 256, 0, stream>>>(src, dst, dis, cnt /*rowfill*/, col, wgt);

  // layer 1: x -> d_out ; layer 2: d_out -> bufA ; layer 3: bufA -> d_out
  k_layer<<<2048, 256, 0, stream>>>(x,    rowptr, col, wgt, dis, W1, b1, out,  1);
  k_layer<<<2048, 256, 0, stream>>>(out,  rowptr, col, wgt, dis, W2, b2, bufA, 1);
  k_layer<<<2048, 256, 0, stream>>>(bufA, rowptr, col, wgt, dis, W3, b3, out,  0);
}

// Round 2
// 573.030 us; speedup vs baseline: 1.0039x; 1.0039x over previous
//
#include <hip/hip_runtime.h>

#define NN 100000
#define NE 1600000
#define DD 64

static constexpr int SCAN_BLOCK = 1024;
static constexpr int NB = (NN + SCAN_BLOCK - 1) / SCAN_BLOCK; // 98

// ---- CSR build ----

__global__ void k_hist(const int* __restrict__ dst, int* __restrict__ cnt) {
  int stride = gridDim.x * blockDim.x;
  for (int i = blockIdx.x * blockDim.x + threadIdx.x; i < NE; i += stride)
    atomicAdd(&cnt[dst[i]], 1);
}

__global__ void k_scan1(const int* __restrict__ cnt, int* __restrict__ rowptr,
                        int* __restrict__ bsum) {
  __shared__ int sh[256];
  int t = threadIdx.x, b = blockIdx.x;
  int base = b * SCAN_BLOCK + t * 4;
  int v0 = (base + 0 < NN) ? cnt[base + 0] : 0;
  int v1 = (base + 1 < NN) ? cnt[base + 1] : 0;
  int v2 = (base + 2 < NN) ? cnt[base + 2] : 0;
  int v3 = (base + 3 < NN) ? cnt[base + 3] : 0;
  int s = v0 + v1 + v2 + v3;
  sh[t] = s;
  __syncthreads();
  for (int off = 1; off < 256; off <<= 1) {
    int x = (t >= off) ? sh[t - off] : 0;
    __syncthreads();
    sh[t] += x;
    __syncthreads();
  }
  int ex = sh[t] - s; // exclusive prefix of this thread's 4-chunk within block
  if (t == 255) bsum[b] = sh[255];
  if (base + 0 < NN) rowptr[base + 0] = ex; ex += v0;
  if (base + 1 < NN) rowptr[base + 1] = ex; ex += v1;
  if (base + 2 < NN) rowptr[base + 2] = ex; ex += v2;
  if (base + 3 < NN) rowptr[base + 3] = ex;
}

// one-block parallel exclusive scan of the 98 block sums
__global__ void k_scan2(int* __restrict__ bsum, int* __restrict__ rowptr) {
  __shared__ int sh[128];
  int t = threadIdx.x;
  int v = (t < NB) ? bsum[t] : 0;
  sh[t] = v;
  __syncthreads();
  for (int off = 1; off < 128; off <<= 1) {
    int x = (t >= off) ? sh[t - off] : 0;
    __syncthreads();
    sh[t] += x;
    __syncthreads();
  }
  if (t < NB) bsum[t] = sh[t] - v;  // exclusive
  if (t == 127) rowptr[NN] = sh[127];
}

// finalize rowptr, init rowfill (reuses cnt), compute dis = rsqrt(deg+1)
__global__ void k_scan3(int* __restrict__ rowptr, const int* __restrict__ bsum,
                        int* __restrict__ cnt_then_rowfill,
                        float* __restrict__ dis) {
  int i = blockIdx.x * blockDim.x + threadIdx.x;
  if (i < NN) {
    float d = rsqrtf((float)(cnt_then_rowfill[i] + 1)); // self-loop included
    int v = rowptr[i] + bsum[i / SCAN_BLOCK];
    rowptr[i] = v;
    cnt_then_rowfill[i] = v;
    dis[i] = d;
  }
}

__global__ void k_fill(const int* __restrict__ src, const int* __restrict__ dst,
                       const float* __restrict__ dis, int* __restrict__ rowfill,
                       int2* __restrict__ edge) {
  int stride = gridDim.x * blockDim.x;
  for (int i = blockIdx.x * blockDim.x + threadIdx.x; i < NE; i += stride) {
    int s = src[i], d = dst[i];
    int pos = atomicAdd(&rowfill[d], 1);
    edge[pos] = make_int2(s, __float_as_int(dis[s] * dis[d]));
  }
}

// ---- pass A: t = h @ W  (streaming GEMM, lane = output feature) ----
__global__ __launch_bounds__(256) void k_xform(const float* __restrict__ h,
                                               const float* __restrict__ W,
                                               float* __restrict__ t) {
  const int lane = threadIdx.x & 63;
  const int wid  = (blockIdx.x * blockDim.x + threadIdx.x) >> 6;
  const int nw   = (gridDim.x * blockDim.x) >> 6;

  float w[64];
  #pragma unroll
  for (int k = 0; k < 64; ++k) w[k] = W[k * 64 + lane];

  for (int r = wid; r < NN; r += nw) {
    float hv = h[(size_t)r * 64 + lane];
    float o0 = 0.f, o1 = 0.f, o2 = 0.f, o3 = 0.f;
    #pragma unroll
    for (int k = 0; k < 64; k += 4) {
      o0 = fmaf(__shfl(hv, k + 0), w[k + 0], o0);
      o1 = fmaf(__shfl(hv, k + 1), w[k + 1], o1);
      o2 = fmaf(__shfl(hv, k + 2), w[k + 2], o2);
      o3 = fmaf(__shfl(hv, k + 3), w[k + 3], o3);
    }
    t[(size_t)r * 64 + lane] = (o0 + o1) + (o2 + o3);
  }
}

// ---- pass B: out = [relu]( S*t + b ) ----
// One wave per node. lane = feature. Edge data promoted to SGPRs via
// readfirstlane so gathers are scalar-base + lane-offset; 8 gathers in
// flight per wave, next edge batch prefetched under the gathers.
__global__ __launch_bounds__(256) void k_agg(
    const float* __restrict__ t, const int* __restrict__ rowptr,
    const int2* __restrict__ edge, const float* __restrict__ dis,
    const float* __restrict__ bias, float* __restrict__ out, int relu)
{
  const int lane = threadIdx.x & 63;
  const int wid  = __builtin_amdgcn_readfirstlane(
                     (int)((blockIdx.x * blockDim.x + threadIdx.x) >> 6));
  const int nw   = (gridDim.x * blockDim.x) >> 6;
  const float bv = bias[lane];

  for (int node = wid; node < NN; node += nw) {
    const int r0 = __builtin_amdgcn_readfirstlane(rowptr[node]);
    const int r1 = __builtin_amdgcn_readfirstlane(rowptr[node + 1]);
    const float di = dis[node];
    float acc = di * di * t[(size_t)node * 64 + lane]; // self-loop: 1/deg

    int2 nb[8];
    #pragma unroll
    for (int u = 0; u < 8; ++u) nb[u] = edge[r0 + u]; // edge has +8 pad

    for (int e = r0; e < r1; ) {
      int   cc[8];
      float ww[8];
      #pragma unroll
      for (int u = 0; u < 8; ++u) {
        bool valid = (e + u) < r1;
        int   c  = __builtin_amdgcn_readfirstlane(nb[u].x);
        int   wb = __builtin_amdgcn_readfirstlane(nb[u].y);
        cc[u] = valid ? c : 0;
        ww[u] = valid ? __int_as_float(wb) : 0.0f;
      }
      int en = e + 8;
      if (en < r1) {
        #pragma unroll
        for (int u = 0; u < 8; ++u) nb[u] = edge[en + u];
      }
      #pragma unroll
      for (int u = 0; u < 8; ++u)
        acc = fmaf(ww[u], t[(size_t)cc[u] * 64 + lane], acc);
      e = en;
    }

    float o = acc + bv;
    if (relu) o = fmaxf(o, 0.0f);
    out[(size_t)node * 64 + lane] = o;
  }
}

extern "C" void kernel_launch(void* const* d_in, const int* in_sizes, int n_in,
                              void* d_out, int out_size, void* d_ws, size_t ws_size,
                              hipStream_t stream) {
  const float* x  = (const float*)d_in[0];
  const int*   ei = (const int*)d_in[1];
  const float* W1 = (const float*)d_in[2];
  const float* b1 = (const float*)d_in[3];
  const float* W2 = (const float*)d_in[4];
  const float* b2 = (const float*)d_in[5];
  const float* W3 = (const float*)d_in[6];
  const float* b3 = (const float*)d_in[7];
  float* out = (float*)d_out;

  const int* src = ei;        // edge_index[0]
  const int* dst = ei + NE;   // edge_index[1]

  char* ws = (char*)d_ws;
  size_t off = 0;
  auto alloc = [&](size_t bytes) {
    void* p = ws + off;
    off = (off + bytes + 255) & ~(size_t)255;
    return p;
  };
  int*   cnt    = (int*)alloc((size_t)NN * 4);          // reused as rowfill
  int*   rowptr = (int*)alloc((size_t)(NN + 1) * 4);
  float* dis    = (float*)alloc((size_t)NN * 4);
  int*   bsum   = (int*)alloc((size_t)NB * 4);
  int2*  edge   = (int2*)alloc((size_t)(NE + 8) * 8);   // +8 pad for masked batches
  float* tbuf   = (float*)alloc((size_t)NN * DD * 4);
  (void)ws_size; (void)in_sizes; (void)n_in; (void)out_size;

  hipMemsetAsync(cnt, 0, (size_t)NN * 4, stream);
  k_hist <<<2048, 256, 0, stream>>>(dst, cnt);
  k_scan1<<<NB, 256, 0, stream>>>(cnt, rowptr, bsum);
  k_scan2<<<1, 128, 0, stream>>>(bsum, rowptr);
  k_scan3<<<(NN + 255) / 256, 256, 0, stream>>>(rowptr, bsum, cnt, dis);
  k_fill <<<2048, 256, 0, stream>>>(src, dst, dis, cnt, edge);

  // layer i: t = h@Wi ; h' = relu(S t + bi)
  k_xform<<<2048, 256, 0, stream>>>(x, W1, tbuf);
  k_agg  <<<4096, 256, 0, stream>>>(tbuf, rowptr, edge, dis, b1, out, 1);
  k_xform<<<2048, 256, 0, stream>>>(out, W2, tbuf);
  k_agg  <<<4096, 256, 0, stream>>>(tbuf, rowptr, edge, dis, b2, out, 1);
  k_xform<<<2048, 256, 0, stream>>>(out, W3, tbuf);
  k_agg  <<<4096, 256, 0, stream>>>(tbuf, rowptr, edge, dis, b3, out, 0);
}

// Round 3
// 474.226 us; speedup vs baseline: 1.2131x; 1.2083x over previous
//
#include <hip/hip_runtime.h>

#define NN 100000
#define NE 1600000

typedef __attribute__((ext_vector_type(16))) int i32x16;
typedef __attribute__((ext_vector_type(2)))  int i32x2;

static constexpr int SCAN_BLOCK = 1024;
static constexpr int NB = (NN + SCAN_BLOCK - 1) / SCAN_BLOCK; // 98

// ---- CSR build ----

__global__ void k_hist(const int4* __restrict__ dst4, int* __restrict__ cnt) {
  int stride = gridDim.x * blockDim.x;
  for (int i = blockIdx.x * blockDim.x + threadIdx.x; i < NE / 4; i += stride) {
    int4 d = dst4[i];
    atomicAdd(&cnt[d.x], 1);
    atomicAdd(&cnt[d.y], 1);
    atomicAdd(&cnt[d.z], 1);
    atomicAdd(&cnt[d.w], 1);
  }
}

__global__ void k_scan1(const int* __restrict__ cnt, int* __restrict__ rowptr,
                        int* __restrict__ bsum) {
  __shared__ int sh[256];
  int t = threadIdx.x, b = blockIdx.x;
  int base = b * SCAN_BLOCK + t * 4;
  int v0 = (base + 0 < NN) ? cnt[base + 0] : 0;
  int v1 = (base + 1 < NN) ? cnt[base + 1] : 0;
  int v2 = (base + 2 < NN) ? cnt[base + 2] : 0;
  int v3 = (base + 3 < NN) ? cnt[base + 3] : 0;
  int s = v0 + v1 + v2 + v3;
  sh[t] = s;
  __syncthreads();
  for (int off = 1; off < 256; off <<= 1) {
    int x = (t >= off) ? sh[t - off] : 0;
    __syncthreads();
    sh[t] += x;
    __syncthreads();
  }
  int ex = sh[t] - s;
  if (t == 255) bsum[b] = sh[255];
  if (base + 0 < NN) rowptr[base + 0] = ex; ex += v0;
  if (base + 1 < NN) rowptr[base + 1] = ex; ex += v1;
  if (base + 2 < NN) rowptr[base + 2] = ex; ex += v2;
  if (base + 3 < NN) rowptr[base + 3] = ex;
}

__global__ void k_scan2(int* __restrict__ bsum, int* __restrict__ rowptr) {
  __shared__ int sh[128];
  int t = threadIdx.x;
  int v = (t < NB) ? bsum[t] : 0;
  sh[t] = v;
  __syncthreads();
  for (int off = 1; off < 128; off <<= 1) {
    int x = (t >= off) ? sh[t - off] : 0;
    __syncthreads();
    sh[t] += x;
    __syncthreads();
  }
  if (t < NB) bsum[t] = sh[t] - v;  // exclusive
  if (t == 127) rowptr[NN] = sh[127];
}

// finalize rowptr, init rowfill (reuses cnt), dis = rsqrt(deg+1)
__global__ void k_scan3(int* __restrict__ rowptr, const int* __restrict__ bsum,
                        int* __restrict__ cnt_then_rowfill, float* __restrict__ dis) {
  int i = blockIdx.x * blockDim.x + threadIdx.x;
  if (i < NN) {
    float d = rsqrtf((float)(cnt_then_rowfill[i] + 1));
    int v = rowptr[i] + bsum[i / SCAN_BLOCK];
    rowptr[i] = v;
    cnt_then_rowfill[i] = v;
    dis[i] = d;
  }
}

__global__ void k_fill(const int4* __restrict__ src4, const int4* __restrict__ dst4,
                       int* __restrict__ rowfill, int* __restrict__ col) {
  int stride = gridDim.x * blockDim.x;
  for (int i = blockIdx.x * blockDim.x + threadIdx.x; i < NE / 4; i += stride) {
    int4 s = src4[i], d = dst4[i];
    col[atomicAdd(&rowfill[d.x], 1)] = s.x;
    col[atomicAdd(&rowfill[d.y], 1)] = s.y;
    col[atomicAdd(&rowfill[d.z], 1)] = s.z;
    col[atomicAdd(&rowfill[d.w], 1)] = s.w;
  }
}

// ---- pass A: t' = dis * (h @ W) ----
// h-row is wave-uniform -> 4x s_load_dwordx16 into 64 SGPRs, FMA with
// per-lane W column. No shuffles, no LDS.
__global__ __launch_bounds__(256) void k_xform(const float* __restrict__ h,
                                               const float* __restrict__ W,
                                               const float* __restrict__ dis,
                                               float* __restrict__ t) {
  const int lane = threadIdx.x & 63;
  const int wid  = __builtin_amdgcn_readfirstlane(
                     (int)((blockIdx.x * blockDim.x + threadIdx.x) >> 6));
  const int nw   = (gridDim.x * blockDim.x) >> 6;

  float w[64];
  #pragma unroll
  for (int k = 0; k < 64; ++k) w[k] = W[k * 64 + lane];

  for (int r = wid; r < NN; r += nw) {
    const float* hp = h + (size_t)r * 64;
    float dr = dis[r];
    i32x16 a, b, c, d;
    asm volatile("s_load_dwordx16 %0, %1, 0x0"  : "=s"(a) : "s"(hp));
    asm volatile("s_load_dwordx16 %0, %1, 0x40" : "=s"(b) : "s"(hp));
    asm volatile("s_load_dwordx16 %0, %1, 0x80" : "=s"(c) : "s"(hp));
    asm volatile("s_load_dwordx16 %0, %1, 0xc0" : "=s"(d) : "s"(hp));
    // SMEM may return out of order: lgkmcnt(0) is the only safe wait.
    // "+s" ties make every consumer data-dependent on this asm (rule #18).
    asm volatile("s_waitcnt lgkmcnt(0)"
                 : "+s"(a), "+s"(b), "+s"(c), "+s"(d));
    float o0 = 0.f, o1 = 0.f, o2 = 0.f, o3 = 0.f;
    #pragma unroll
    for (int k = 0; k < 16; ++k) {
      o0 = fmaf(__int_as_float(a[k]), w[k],      o0);
      o1 = fmaf(__int_as_float(b[k]), w[16 + k], o1);
      o2 = fmaf(__int_as_float(c[k]), w[32 + k], o2);
      o3 = fmaf(__int_as_float(d[k]), w[48 + k], o3);
    }
    t[(size_t)r * 64 + lane] = ((o0 + o1) + (o2 + o3)) * dr;
  }
}

// ---- pass B: out = [relu]( dis_d * (sum_e t'[src_e] + t'[d]) + b ) ----
// Edges are plain src indices; 16 per s_load_dwordx16. Gathers use
// SGPR base + lane offset; 16 loads in flight; 4 accumulator chains.
__global__ __launch_bounds__(256) void k_agg(
    const float* __restrict__ t, const int* __restrict__ rowptr,
    const int* __restrict__ col, const float* __restrict__ dis,
    const float* __restrict__ bias, float* __restrict__ out, int relu)
{
  const int lane = threadIdx.x & 63;
  const int wid  = __builtin_amdgcn_readfirstlane(
                     (int)((blockIdx.x * blockDim.x + threadIdx.x) >> 6));
  const int nw   = (gridDim.x * blockDim.x) >> 6;
  const float bv = bias[lane];

  for (int node = wid; node < NN; node += nw) {
    const int* rp = rowptr + node;
    i32x2 r01;
    asm volatile("s_load_dwordx2 %0, %1, 0x0\n\ts_waitcnt lgkmcnt(0)"
                 : "=s"(r01) : "s"(rp));
    const int r0 = r01[0], r1 = r01[1];
    const float dn = dis[node];
    float a0 = t[(size_t)node * 64 + lane];  // self (t' is pre-scaled)
    float a1 = 0.f, a2 = 0.f, a3 = 0.f;

    for (int e = r0; e < r1; e += 16) {
      const int* ep = col + e;
      i32x16 eb;
      asm volatile("s_load_dwordx16 %0, %1, 0x0\n\ts_waitcnt lgkmcnt(0)"
                   : "=s"(eb) : "s"(ep));
      float g[16];
      #pragma unroll
      for (int u = 0; u < 16; ++u) {
        int c = (e + u < r1) ? eb[u] : 0;   // clamp tail (uniform cselect)
        g[u] = t[(size_t)c * 64 + lane];
      }
      #pragma unroll
      for (int u = 0; u < 16; u += 4) {
        a0 += (e + u + 0 < r1) ? g[u + 0] : 0.f;
        a1 += (e + u + 1 < r1) ? g[u + 1] : 0.f;
        a2 += (e + u + 2 < r1) ? g[u + 2] : 0.f;
        a3 += (e + u + 3 < r1) ? g[u + 3] : 0.f;
      }
    }

    float o = fmaf(dn, (a0 + a1) + (a2 + a3), bv);
    if (relu) o = fmaxf(o, 0.0f);
    out[(size_t)node * 64 + lane] = o;
  }
}

extern "C" void kernel_launch(void* const* d_in, const int* in_sizes, int n_in,
                              void* d_out, int out_size, void* d_ws, size_t ws_size,
                              hipStream_t stream) {
  const float* x  = (const float*)d_in[0];
  const int*   ei = (const int*)d_in[1];
  const float* W1 = (const float*)d_in[2];
  const float* b1 = (const float*)d_in[3];
  const float* W2 = (const float*)d_in[4];
  const float* b2 = (const float*)d_in[5];
  const float* W3 = (const float*)d_in[6];
  const float* b3 = (const float*)d_in[7];
  float* out = (float*)d_out;

  const int* src = ei;        // edge_index[0]
  const int* dst = ei + NE;   // edge_index[1]

  char* ws = (char*)d_ws;
  size_t off = 0;
  auto alloc = [&](size_t bytes) {
    void* p = ws + off;
    off = (off + bytes + 255) & ~(size_t)255;
    return p;
  };
  int*   cnt    = (int*)alloc((size_t)NN * 4);          // reused as rowfill
  int*   rowptr = (int*)alloc((size_t)(NN + 1) * 4);
  float* dis    = (float*)alloc((size_t)NN * 4);
  int*   bsum   = (int*)alloc((size_t)NB * 4);
  int*   col    = (int*)alloc((size_t)(NE + 16) * 4);   // +16 pad for s_load overrun
  float* tbuf   = (float*)alloc((size_t)NN * 64 * 4);
  (void)ws_size; (void)in_sizes; (void)n_in; (void)out_size;

  hipMemsetAsync(cnt, 0, (size_t)NN * 4, stream);
  k_hist <<<1024, 256, 0, stream>>>((const int4*)dst, cnt);
  k_scan1<<<NB, 256, 0, stream>>>(cnt, rowptr, bsum);
  k_scan2<<<1, 128, 0, stream>>>(bsum, rowptr);
  k_scan3<<<(NN + 255) / 256, 256, 0, stream>>>(rowptr, bsum, cnt, dis);
  k_fill <<<1024, 256, 0, stream>>>((const int4*)src, (const int4*)dst, cnt, col);

  // layer i: t' = dis*(h@Wi) ; h' = relu(dis*(S_sum t') + bi)
  k_xform<<<2048, 256, 0, stream>>>(x,   W1, dis, tbuf);
  k_agg  <<<4096, 256, 0, stream>>>(tbuf, rowptr, col, dis, b1, out, 1);
  k_xform<<<2048, 256, 0, stream>>>(out, W2, dis, tbuf);
  k_agg  <<<4096, 256, 0, stream>>>(tbuf, rowptr, col, dis, b2, out, 1);
  k_xform<<<2048, 256, 0, stream>>>(out, W3, dis, tbuf);
  k_agg  <<<4096, 256, 0, stream>>>(tbuf, rowptr, col, dis, b3, out, 0);
}

// Round 4
// 350.224 us; speedup vs baseline: 1.6426x; 1.3541x over previous
//
#include <hip/hip_runtime.h>

#define NN 100000
#define NE 1600000

typedef __attribute__((ext_vector_type(16))) int i32x16;
typedef __attribute__((ext_vector_type(2)))  int i32x2;

// ---- bucketed CSR build ----
// bucket = dst >> 9  (512 nodes per bucket)
#define NBKT 196                 // ceil(100000 / 512)
#define NBLK 128                 // partition blocks
#define EPB  (NE / NBLK)         // 12500 edges per partition block
#define PTH  512                 // threads in partition/bucket kernels

// per-block bucket histogram (LDS atomics only)
__global__ __launch_bounds__(PTH) void k_pcount(const int* __restrict__ dst,
                                                int* __restrict__ pcount) {
  __shared__ int lcnt[NBKT];
  int t = threadIdx.x, b = blockIdx.x;
  for (int i = t; i < NBKT; i += PTH) lcnt[i] = 0;
  __syncthreads();
  int base = b * EPB;
  for (int i = t; i < EPB; i += PTH)
    atomicAdd(&lcnt[dst[base + i] >> 9], 1);
  __syncthreads();
  for (int i = t; i < NBKT; i += PTH)
    pcount[i * NBLK + b] = lcnt[i];   // bucket-major layout
}

// exclusive scan of the 196*128 = 25088-entry table, one block
__global__ __launch_bounds__(1024) void k_pscan(int* __restrict__ pcount) {
  __shared__ int sh[1024];
  const int TOT = NBKT * NBLK;
  int t = threadIdx.x;
  int base = t * 25;
  int v[25];
  int s = 0;
  #pragma unroll
  for (int k = 0; k < 25; ++k) {
    v[k] = (base + k < TOT) ? pcount[base + k] : 0;
    s += v[k];
  }
  sh[t] = s;
  __syncthreads();
  for (int off = 1; off < 1024; off <<= 1) {
    int x = (t >= off) ? sh[t - off] : 0;
    __syncthreads();
    sh[t] += x;
    __syncthreads();
  }
  int ex = sh[t] - s;
  #pragma unroll
  for (int k = 0; k < 25; ++k) {
    if (base + k < TOT) pcount[base + k] = ex;
    ex += v[k];
  }
}

// scatter edges into bucket-grouped staging; each block owns 196 private
// sequential streams -> write frontier is L2-resident, full-line writeback
__global__ __launch_bounds__(PTH) void k_pscatter(const int* __restrict__ src,
                                                  const int* __restrict__ dst,
                                                  const int* __restrict__ pcount,
                                                  int2* __restrict__ staged) {
  __shared__ int lpos[NBKT];
  int t = threadIdx.x, b = blockIdx.x;
  for (int i = t; i < NBKT; i += PTH) lpos[i] = pcount[i * NBLK + b];
  __syncthreads();
  int base = b * EPB;
  for (int i = t; i < EPB; i += PTH) {
    int s = src[base + i], d = dst[base + i];
    int pos = atomicAdd(&lpos[d >> 9], 1);
    staged[pos] = make_int2(s, d);
  }
}

// per-bucket: LDS node histogram -> in-block scan gives rowptr directly
// (bucket's CSR base == bucket's staging base), then L2-local col scatter.
// Also emits dis = rsqrt(deg+1). Replaces global scan + fill + dis kernels.
__global__ __launch_bounds__(PTH) void k_bucket(const int2* __restrict__ staged,
                                                const int* __restrict__ pcount,
                                                int* __restrict__ rowptr,
                                                float* __restrict__ dis,
                                                int* __restrict__ col) {
  __shared__ int lcnt[PTH];
  __shared__ int lscan[PTH];
  __shared__ int lpos[PTH];
  int t = threadIdx.x, bkt = blockIdx.x;
  int sbeg = pcount[bkt * NBLK];
  int send = (bkt == NBKT - 1) ? NE : pcount[(bkt + 1) * NBLK];

  lcnt[t] = 0;
  __syncthreads();
  for (int i = sbeg + t; i < send; i += PTH)
    atomicAdd(&lcnt[staged[i].y & 511], 1);
  __syncthreads();

  int v = lcnt[t];
  lscan[t] = v;
  __syncthreads();
  for (int off = 1; off < PTH; off <<= 1) {
    int x = (t >= off) ? lscan[t - off] : 0;
    __syncthreads();
    lscan[t] += x;
    __syncthreads();
  }
  int gbase = sbeg + lscan[t] - v;   // exclusive prefix within bucket
  int node = bkt * 512 + t;
  if (node < NN) {
    rowptr[node] = gbase;
    dis[node] = rsqrtf((float)(v + 1));  // +1 self-loop
  }
  lpos[t] = gbase;
  if (bkt == NBKT - 1 && t == 0) rowptr[NN] = NE;
  __syncthreads();

  for (int i = sbeg + t; i < send; i += PTH) {
    int2 e = staged[i];                       // L2-hot re-read
    col[atomicAdd(&lpos[e.y & 511], 1)] = e.x;
  }
}

// ---- pass A: t' = dis * (h @ W) ----
__global__ __launch_bounds__(256) void k_xform(const float* __restrict__ h,
                                               const float* __restrict__ W,
                                               const float* __restrict__ dis,
                                               float* __restrict__ t) {
  const int lane = threadIdx.x & 63;
  const int wid  = __builtin_amdgcn_readfirstlane(
                     (int)((blockIdx.x * blockDim.x + threadIdx.x) >> 6));
  const int nw   = (gridDim.x * blockDim.x) >> 6;

  float w[64];
  #pragma unroll
  for (int k = 0; k < 64; ++k) w[k] = W[k * 64 + lane];

  for (int r = wid; r < NN; r += nw) {
    const float* hp = h + (size_t)r * 64;
    float dr = dis[r];
    i32x16 a, b, c, d;
    asm volatile("s_load_dwordx16 %0, %1, 0x0"  : "=s"(a) : "s"(hp));
    asm volatile("s_load_dwordx16 %0, %1, 0x40" : "=s"(b) : "s"(hp));
    asm volatile("s_load_dwordx16 %0, %1, 0x80" : "=s"(c) : "s"(hp));
    asm volatile("s_load_dwordx16 %0, %1, 0xc0" : "=s"(d) : "s"(hp));
    asm volatile("s_waitcnt lgkmcnt(0)"
                 : "+s"(a), "+s"(b), "+s"(c), "+s"(d));
    float o0 = 0.f, o1 = 0.f, o2 = 0.f, o3 = 0.f;
    #pragma unroll
    for (int k = 0; k < 16; ++k) {
      o0 = fmaf(__int_as_float(a[k]), w[k],      o0);
      o1 = fmaf(__int_as_float(b[k]), w[16 + k], o1);
      o2 = fmaf(__int_as_float(c[k]), w[32 + k], o2);
      o3 = fmaf(__int_as_float(d[k]), w[48 + k], o3);
    }
    t[(size_t)r * 64 + lane] = ((o0 + o1) + (o2 + o3)) * dr;
  }
}

// ---- pass B: out = [relu]( dis_d * (sum_e t'[src_e] + t'[d]) + b ) ----
__global__ __launch_bounds__(256) void k_agg(
    const float* __restrict__ t, const int* __restrict__ rowptr,
    const int* __restrict__ col, const float* __restrict__ dis,
    const float* __restrict__ bias, float* __restrict__ out, int relu)
{
  const int lane = threadIdx.x & 63;
  const int wid  = __builtin_amdgcn_readfirstlane(
                     (int)((blockIdx.x * blockDim.x + threadIdx.x) >> 6));
  const int nw   = (gridDim.x * blockDim.x) >> 6;
  const float bv = bias[lane];

  for (int node = wid; node < NN; node += nw) {
    const int* rp = rowptr + node;
    i32x2 r01;
    asm volatile("s_load_dwordx2 %0, %1, 0x0\n\ts_waitcnt lgkmcnt(0)"
                 : "=s"(r01) : "s"(rp));
    const int r0 = r01[0], r1 = r01[1];
    const float dn = dis[node];
    float a0 = t[(size_t)node * 64 + lane];  // self (t' pre-scaled)
    float a1 = 0.f, a2 = 0.f, a3 = 0.f;

    for (int e = r0; e < r1; e += 16) {
      const int* ep = col + e;
      i32x16 eb;
      asm volatile("s_load_dwordx16 %0, %1, 0x0\n\ts_waitcnt lgkmcnt(0)"
                   : "=s"(eb) : "s"(ep));
      float g[16];
      #pragma unroll
      for (int u = 0; u < 16; ++u) {
        int c = (e + u < r1) ? eb[u] : 0;
        g[u] = t[(size_t)c * 64 + lane];
      }
      #pragma unroll
      for (int u = 0; u < 16; u += 4) {
        a0 += (e + u + 0 < r1) ? g[u + 0] : 0.f;
        a1 += (e + u + 1 < r1) ? g[u + 1] : 0.f;
        a2 += (e + u + 2 < r1) ? g[u + 2] : 0.f;
        a3 += (e + u + 3 < r1) ? g[u + 3] : 0.f;
      }
    }

    float o = fmaf(dn, (a0 + a1) + (a2 + a3), bv);
    if (relu) o = fmaxf(o, 0.0f);
    out[(size_t)node * 64 + lane] = o;
  }
}

extern "C" void kernel_launch(void* const* d_in, const int* in_sizes, int n_in,
                              void* d_out, int out_size, void* d_ws, size_t ws_size,
                              hipStream_t stream) {
  const float* x  = (const float*)d_in[0];
  const int*   ei = (const int*)d_in[1];
  const float* W1 = (const float*)d_in[2];
  const float* b1 = (const float*)d_in[3];
  const float* W2 = (const float*)d_in[4];
  const float* b2 = (const float*)d_in[5];
  const float* W3 = (const float*)d_in[6];
  const float* b3 = (const float*)d_in[7];
  float* out = (float*)d_out;

  const int* src = ei;        // edge_index[0]
  const int* dst = ei + NE;   // edge_index[1]

  char* ws = (char*)d_ws;
  size_t off = 0;
  auto alloc = [&](size_t bytes) {
    void* p = ws + off;
    off = (off + bytes + 255) & ~(size_t)255;
    return p;
  };
  int*   pcount = (int*)alloc((size_t)NBKT * NBLK * 4);
  int*   rowptr = (int*)alloc((size_t)(NN + 1) * 4);
  float* dis    = (float*)alloc((size_t)NN * 4);
  int2*  staged = (int2*)alloc((size_t)NE * 8);
  int*   col    = (int*)alloc((size_t)(NE + 16) * 4);   // +16: s_load overrun pad
  float* tbuf   = (float*)alloc((size_t)NN * 64 * 4);
  (void)ws_size; (void)in_sizes; (void)n_in; (void)out_size;

  k_pcount  <<<NBLK, PTH, 0, stream>>>(dst, pcount);
  k_pscan   <<<1, 1024, 0, stream>>>(pcount);
  k_pscatter<<<NBLK, PTH, 0, stream>>>(src, dst, pcount, staged);
  k_bucket  <<<NBKT, PTH, 0, stream>>>(staged, pcount, rowptr, dis, col);

  // layer i: t' = dis*(h@Wi) ; h' = relu(dis*(S_sum t') + bi)
  k_xform<<<2048, 256, 0, stream>>>(x,   W1, dis, tbuf);
  k_agg  <<<4096, 256, 0, stream>>>(tbuf, rowptr, col, dis, b1, out, 1);
  k_xform<<<2048, 256, 0, stream>>>(out, W2, dis, tbuf);
  k_agg  <<<4096, 256, 0, stream>>>(tbuf, rowptr, col, dis, b2, out, 1);
  k_xform<<<2048, 256, 0, stream>>>(out, W3, dis, tbuf);
  k_agg  <<<4096, 256, 0, stream>>>(tbuf, rowptr, col, dis, b3, out, 0);
}